// Round 2
// baseline (295.683 us; speedup 1.0000x reference)
//
#include <hip/hip_runtime.h>
#include <stdint.h>

typedef unsigned short u16;
typedef __attribute__((ext_vector_type(8))) short short8v;
typedef __attribute__((ext_vector_type(4))) float f32x4;

#define NBATCH 16
#define KLEN 2048
#define DDIM 512
#define NTILE 64     // tiles per batch
#define TROWS 32     // rows per tile (NTILE*TROWS == KLEN)
#define TEMP_INV (1.0f / 22.627418f)   // 1/(sqrt(512)+1e-6)

static __device__ __forceinline__ u16 f2bf(float f) {
  union { float f; uint32_t u; } a; a.f = f;
  uint32_t r = a.u + 0x7FFFu + ((a.u >> 16) & 1u);   // RNE
  return (u16)(r >> 16);
}
static __device__ __forceinline__ float bf2f(u16 h) {
  union { uint32_t u; float f; } a; a.u = ((uint32_t)h) << 16;
  return a.f;
}

// ---------------- K0a: u[b] = W_k @ (Q[b] @ W_q) ----------------
__global__ __launch_bounds__(512) void k_qu(const float* __restrict__ Q,
    const float* __restrict__ Wq, const float* __restrict__ Wk,
    float* __restrict__ u) {
  int b = blockIdx.x, t = threadIdx.x;
  __shared__ float qs[DDIM];
  __shared__ float q2[DDIM];
  qs[t] = Q[b * DDIM + t];
  __syncthreads();
  {
    float acc = 0.f;
    for (int e = 0; e < DDIM; ++e) acc = fmaf(qs[e], Wq[e * DDIM + t], acc);
    q2[t] = acc;
  }
  __syncthreads();
  {
    float acc = 0.f;
    const float* row = Wk + t * DDIM;
    for (int d0 = 0; d0 < DDIM; d0 += 4) {
      float4 wv = *reinterpret_cast<const float4*>(row + d0);
      acc = fmaf(wv.x, q2[d0], acc);
      acc = fmaf(wv.y, q2[d0 + 1], acc);
      acc = fmaf(wv.z, q2[d0 + 2], acc);
      acc = fmaf(wv.w, q2[d0 + 3], acc);
    }
    u[b * DDIM + t] = acc;
  }
}

// ---------------- K0b: W_v -> bf16, MFMA-fragment-swizzled ----------------
// chunk index = kb*32 + ni ; lane l holds B[k=kb*32+(l>>4)*8+j][n=ni*16+(l&15)]
__global__ void k_wswz(const float* __restrict__ Wv, u16* __restrict__ Wf) {
  int blk = blockIdx.x;      // 0..511
  int l = threadIdx.x;       // 0..63
  int kb = blk >> 5, ni = blk & 31;
  int n = ni * 16 + (l & 15);
  int k0 = kb * 32 + (l >> 4) * 8;
  union { short8v v; u16 s[8]; } tmp;
#pragma unroll
  for (int j = 0; j < 8; ++j) tmp.s[j] = f2bf(Wv[(k0 + j) * DDIM + n]);
  *reinterpret_cast<short8v*>(Wf + (blk * 64 + l) * 8) = tmp.v;
}

// ---------------- K1: s[b,k] = K[b,k,:].u[b] / temp  (1 wave/row) ----------
__global__ __launch_bounds__(256) void k_scores(const float* __restrict__ Kin,
    const float* __restrict__ u, float* __restrict__ s) {
  int wid = threadIdx.x >> 6, lane = threadIdx.x & 63;
  int row = blockIdx.x * 4 + wid;        // < 32768
  int b = row >> 11;
  const float* kr = Kin + row * DDIM + lane * 8;
  const float* ur = u + b * DDIM + lane * 8;
  float4 k0 = *reinterpret_cast<const float4*>(kr);
  float4 k1 = *reinterpret_cast<const float4*>(kr + 4);
  float4 u0 = *reinterpret_cast<const float4*>(ur);
  float4 u1 = *reinterpret_cast<const float4*>(ur + 4);
  float dot = k0.x * u0.x + k0.y * u0.y + k0.z * u0.z + k0.w * u0.w
            + k1.x * u1.x + k1.y * u1.y + k1.z * u1.z + k1.w * u1.w;
#pragma unroll
  for (int off = 32; off; off >>= 1) dot += __shfl_xor(dot, off);
  if (lane == 0) s[row] = dot * TEMP_INV;
}

// ---------------- K1b: per-batch max, w = exp(s - M) ----------------
__global__ __launch_bounds__(256) void k_expw(const float* __restrict__ s,
    float* __restrict__ w) {
  int b = blockIdx.x, t = threadIdx.x;
  __shared__ float red[4];
  float v[8];
  float m = -3e38f;
#pragma unroll
  for (int i = 0; i < 8; ++i) { v[i] = s[b * KLEN + t * 8 + i]; m = fmaxf(m, v[i]); }
#pragma unroll
  for (int off = 32; off; off >>= 1) m = fmaxf(m, __shfl_xor(m, off));
  if ((t & 63) == 0) red[t >> 6] = m;
  __syncthreads();
  float M = fmaxf(fmaxf(red[0], red[1]), fmaxf(red[2], red[3]));
#pragma unroll
  for (int i = 0; i < 8; ++i) w[b * KLEN + t * 8 + i] = __expf(v[i] - M);
}

// ---------------- K2: V' = V @ W_v  (bf16 MFMA 16x16x32, 128x128 tile) -----
__global__ __launch_bounds__(256, 2) void k_gemm(const float* __restrict__ V,
    const u16* __restrict__ Wf, u16* __restrict__ Vp) {
  int rt = blockIdx.x;   // 0..255 : 128 rows
  int ct = blockIdx.y;   // 0..3   : 128 cols
  __shared__ __align__(16) u16 Asm[4096];   // [mi(8)][lane(64)][8] bf16
  __shared__ __align__(16) u16 Bsm[4096];   // [ni(8)][lane(64)][8] bf16
  int t = threadIdx.x;
  int wid = t >> 6, lane = t & 63;
  int wm = wid >> 1, wn = wid & 1;

  f32x4 zero4 = {0.f, 0.f, 0.f, 0.f};
  f32x4 acc[4][4];
#pragma unroll
  for (int i = 0; i < 4; ++i)
#pragma unroll
    for (int j = 0; j < 4; ++j) acc[i][j] = zero4;

  int m_ = t >> 2;            // 0..63
  int k0_ = (t & 3) * 8;      // 0,8,16,24
  const float* Abase = V + rt * 128 * DDIM;

  for (int kb = 0; kb < 16; ++kb) {
    __syncthreads();
    // stage A: fp32 load -> bf16 -> fragment-linear LDS
#pragma unroll
    for (int half = 0; half < 2; ++half) {
      int mm = m_ + half * 64;
      const float* src = Abase + mm * DDIM + kb * 32 + k0_;
      float4 f0 = *reinterpret_cast<const float4*>(src);
      float4 f1 = *reinterpret_cast<const float4*>(src + 4);
      union { short8v v; u16 sb[8]; } tmp;
      tmp.sb[0] = f2bf(f0.x); tmp.sb[1] = f2bf(f0.y);
      tmp.sb[2] = f2bf(f0.z); tmp.sb[3] = f2bf(f0.w);
      tmp.sb[4] = f2bf(f1.x); tmp.sb[5] = f2bf(f1.y);
      tmp.sb[6] = f2bf(f1.z); tmp.sb[7] = f2bf(f1.w);
      int idx = (((mm >> 4) << 6) + ((t & 3) << 4) + (mm & 15)) << 3;
      *reinterpret_cast<short8v*>(&Asm[idx]) = tmp.v;
    }
    // stage B: pre-swizzled bf16, 16B per thread, 2 chunks
    {
      int i2 = t;
      *reinterpret_cast<short8v*>(&Bsm[i2 * 8]) =
          *reinterpret_cast<const short8v*>(Wf + ((kb * 32 + ct * 8) * 64 + i2) * 8);
      i2 = t + 256;
      *reinterpret_cast<short8v*>(&Bsm[i2 * 8]) =
          *reinterpret_cast<const short8v*>(Wf + ((kb * 32 + ct * 8) * 64 + i2) * 8);
    }
    __syncthreads();
    short8v af[4], bfr[4];
#pragma unroll
    for (int i = 0; i < 4; ++i)
      af[i] = *reinterpret_cast<const short8v*>(&Asm[((wm * 4 + i) * 64 + lane) * 8]);
#pragma unroll
    for (int j = 0; j < 4; ++j)
      bfr[j] = *reinterpret_cast<const short8v*>(&Bsm[((wn * 4 + j) * 64 + lane) * 8]);
#pragma unroll
    for (int i = 0; i < 4; ++i)
#pragma unroll
      for (int j = 0; j < 4; ++j)
        acc[i][j] = __builtin_amdgcn_mfma_f32_16x16x32_bf16(af[i], bfr[j], acc[i][j], 0, 0, 0);
  }
  // epilogue: D[row=(l>>4)*4+r][col=l&15] per fragment
  int r0 = rt * 128 + wm * 64;
  int c0 = ct * 128 + wn * 64;
#pragma unroll
  for (int i = 0; i < 4; ++i)
#pragma unroll
    for (int j = 0; j < 4; ++j)
#pragma unroll
      for (int r = 0; r < 4; ++r) {
        int row = r0 + i * 16 + (lane >> 4) * 4 + r;
        int col = c0 + j * 16 + (lane & 15);
        Vp[row * DDIM + col] = f2bf(acc[i][j][r]);
      }
}

// ---------------- K3 (pass A): per-tile weighted / unweighted sums ---------
__global__ __launch_bounds__(512) void k_tilesum(const u16* __restrict__ Vp,
    const float* __restrict__ w, float* __restrict__ S, float* __restrict__ U,
    float* __restrict__ z) {
  int bt = blockIdx.x;          // b*NTILE + t ; global row base = bt*TROWS
  int d = threadIdx.x;
  int krow0 = bt * TROWS;
  const float* wrow = w + krow0;
  const u16* vbase = Vp + krow0 * DDIM + d;
  float Sa = 0.f, Ua = 0.f, za = 0.f;
#pragma unroll 4
  for (int r = 0; r < TROWS; ++r) {
    float wk = wrow[r];
    float v = bf2f(vbase[r * DDIM]);
    Sa = fmaf(wk, v, Sa);
    Ua += v;
    za += wk;
  }
  S[bt * DDIM + d] = Sa;
  U[bt * DDIM + d] = Ua;
  if (d == 0) z[bt] = za;
}

// ---------------- K4: exclusive prefix over tiles + column mean ------------
__global__ __launch_bounds__(512) void k_prefix(const float* __restrict__ S,
    const float* __restrict__ U, const float* __restrict__ z,
    float* __restrict__ base_, float* __restrict__ zbase,
    float* __restrict__ meanVp) {
  int b = blockIdx.x, d = threadIdx.x;
  float acc = 0.f, tot = 0.f, zacc = 0.f;
  for (int tt = 0; tt < NTILE; ++tt) {
    int bt = b * NTILE + tt;
    base_[bt * DDIM + d] = acc;
    if (d == 0) zbase[bt] = zacc;
    acc += S[bt * DDIM + d];
    zacc += z[bt];
    tot += U[bt * DDIM + d];
  }
  meanVp[b * DDIM + d] = tot * (1.0f / KLEN);
}

// ---------------- K5 (pass B): in-tile scan + V-add + LayerNorm ------------
__global__ __launch_bounds__(512, 2) void k_scan(const u16* __restrict__ Vp,
    const float* __restrict__ Vin, const float* __restrict__ w,
    const int* __restrict__ mask, const float* __restrict__ base_,
    const float* __restrict__ zbase, const float* __restrict__ meanVp,
    const float* __restrict__ gamma, const float* __restrict__ beta,
    float* __restrict__ out) {
  int bt = blockIdx.x;
  int b = bt >> 6;
  int d = threadIdx.x;
  __shared__ float xs[TROWS][DDIM];   // 64 KiB
  float acc = base_[bt * DDIM + d];
  float zacc = zbase[bt];
  float mv = meanVp[b * DDIM + d];
  int krow0 = bt * TROWS;
  for (int r = 0; r < TROWS; ++r) {
    int k = krow0 + r;
    float wk = w[k];
    zacc += wk;
    float v_ = bf2f(Vp[k * DDIM + d]);
    acc = fmaf(wk, v_, acc);
    float vatt = mask[k] ? mv : acc * __builtin_amdgcn_rcpf(zacc);
    xs[r][d] = Vin[k * DDIM + d] + vatt;
  }
  __syncthreads();
  // LN phase: lane l handles cols [l*4, l*4+3] and [256+l*4, 256+l*4+3]
  // (contiguous 1024B per wave per ds_read_b128 -> no bank conflicts)
  int wid = d >> 6, lane = d & 63;
  float4 g0 = *reinterpret_cast<const float4*>(gamma + lane * 4);
  float4 g1 = *reinterpret_cast<const float4*>(gamma + 256 + lane * 4);
  float4 b0 = *reinterpret_cast<const float4*>(beta + lane * 4);
  float4 b1 = *reinterpret_cast<const float4*>(beta + 256 + lane * 4);
#pragma unroll
  for (int rr = 0; rr < 4; ++rr) {
    int r = wid * 4 + rr;
    float4 x0 = *reinterpret_cast<const float4*>(&xs[r][lane * 4]);
    float4 x1 = *reinterpret_cast<const float4*>(&xs[r][256 + lane * 4]);
    float sum = x0.x + x0.y + x0.z + x0.w + x1.x + x1.y + x1.z + x1.w;
    float sq = x0.x * x0.x + x0.y * x0.y + x0.z * x0.z + x0.w * x0.w
             + x1.x * x1.x + x1.y * x1.y + x1.z * x1.z + x1.w * x1.w;
#pragma unroll
    for (int off = 32; off; off >>= 1) {
      sum += __shfl_xor(sum, off);
      sq += __shfl_xor(sq, off);
    }
    float mu = sum * (1.0f / DDIM);
    float var = sq * (1.0f / DDIM) - mu * mu;
    float rstd = rsqrtf(var + 1e-5f);
    int k = krow0 + r;
    float* orow = out + k * DDIM;
    float4 o0, o1;
    o0.x = (x0.x - mu) * rstd * g0.x + b0.x;
    o0.y = (x0.y - mu) * rstd * g0.y + b0.y;
    o0.z = (x0.z - mu) * rstd * g0.z + b0.z;
    o0.w = (x0.w - mu) * rstd * g0.w + b0.w;
    o1.x = (x1.x - mu) * rstd * g1.x + b1.x;
    o1.y = (x1.y - mu) * rstd * g1.y + b1.y;
    o1.z = (x1.z - mu) * rstd * g1.z + b1.z;
    o1.w = (x1.w - mu) * rstd * g1.w + b1.w;
    *reinterpret_cast<float4*>(orow + lane * 4) = o0;
    *reinterpret_cast<float4*>(orow + 256 + lane * 4) = o1;
  }
}

extern "C" void kernel_launch(void* const* d_in, const int* in_sizes, int n_in,
                              void* d_out, int out_size, void* d_ws, size_t ws_size,
                              hipStream_t stream) {
  const float* Q     = (const float*)d_in[0];
  const float* Kin   = (const float*)d_in[1];
  const float* Vin   = (const float*)d_in[2];
  const int*   mask  = (const int*)d_in[3];
  const float* Wq    = (const float*)d_in[4];
  const float* Wk    = (const float*)d_in[5];
  const float* Wv    = (const float*)d_in[6];
  const float* gamma = (const float*)d_in[7];
  const float* beta  = (const float*)d_in[8];
  float* out = (float*)d_out;

  char* p = (char*)d_ws;
  float* u      = (float*)p; p += NBATCH * DDIM * 4;
  u16*   Wf     = (u16*)p;   p += DDIM * DDIM * 2;
  float* s      = (float*)p; p += NBATCH * KLEN * 4;
  float* w      = (float*)p; p += NBATCH * KLEN * 4;
  float* S      = (float*)p; p += NBATCH * NTILE * DDIM * 4;
  float* U      = (float*)p; p += NBATCH * NTILE * DDIM * 4;
  float* base_  = (float*)p; p += NBATCH * NTILE * DDIM * 4;
  float* z      = (float*)p; p += NBATCH * NTILE * 4;
  float* zbase  = (float*)p; p += NBATCH * NTILE * 4;
  float* meanVp = (float*)p; p += NBATCH * DDIM * 4;
  u16*   Vp     = (u16*)p;   p += (size_t)NBATCH * KLEN * DDIM * 2;

  k_qu<<<NBATCH, 512, 0, stream>>>(Q, Wq, Wk, u);
  k_wswz<<<512, 64, 0, stream>>>(Wv, Wf);
  k_scores<<<(NBATCH * KLEN) / 4, 256, 0, stream>>>(Kin, u, s);
  k_expw<<<NBATCH, 256, 0, stream>>>(s, w);
  k_gemm<<<dim3(256, 4), 256, 0, stream>>>(Vin, Wf, Vp);
  k_tilesum<<<NBATCH * NTILE, 512, 0, stream>>>(Vp, w, S, U, z);
  k_prefix<<<NBATCH, 512, 0, stream>>>(S, U, z, base_, zbase, meanVp);
  k_scan<<<NBATCH * NTILE, 512, 0, stream>>>(Vp, Vin, w, mask, base_, zbase,
                                             meanVp, gamma, beta, out);
}

// Round 3
// 263.846 us; speedup vs baseline: 1.1207x; 1.1207x over previous
//
#include <hip/hip_runtime.h>
#include <stdint.h>

typedef unsigned short u16;
typedef __attribute__((ext_vector_type(8))) short short8v;
typedef __attribute__((ext_vector_type(4))) float f32x4;

#define NBATCH 16
#define KLEN 2048
#define DDIM 512
#define NTILE 64     // tiles per batch
#define TROWS 32     // rows per tile (NTILE*TROWS == KLEN)
#define TEMP_INV (1.0f / 22.627418f)   // 1/(sqrt(512)+1e-6)

static __device__ __forceinline__ u16 f2bf(float f) {
  union { float f; uint32_t u; } a; a.f = f;
  uint32_t r = a.u + 0x7FFFu + ((a.u >> 16) & 1u);   // RNE
  return (u16)(r >> 16);
}
static __device__ __forceinline__ float bf2f(u16 h) {
  union { uint32_t u; float f; } a; a.u = ((uint32_t)h) << 16;
  return a.f;
}

// ---------------- K0a-1: q2[b,d] = sum_e Q[b,e] Wq[e,d]  (split-K atomic) --
// grid 64 = 8 d-chunks x 8 e-chunks; 64 threads; q2 pre-zeroed by memset.
__global__ __launch_bounds__(64) void k_qu1(const float* __restrict__ Q,
    const float* __restrict__ Wq, float* __restrict__ q2) {
  int dc = blockIdx.x & 7, ec = blockIdx.x >> 3;
  int lane = threadIdx.x;
  int d = dc * 64 + lane;
  __shared__ float Qs[NBATCH][64];
  for (int i = lane; i < NBATCH * 64; i += 64) {
    int b = i >> 6, e = i & 63;
    Qs[b][e] = Q[b * DDIM + ec * 64 + e];
  }
  __syncthreads();
  float acc[NBATCH];
#pragma unroll
  for (int b = 0; b < NBATCH; ++b) acc[b] = 0.f;
#pragma unroll 4
  for (int e = 0; e < 64; ++e) {
    float wq = Wq[(ec * 64 + e) * DDIM + d];
#pragma unroll
    for (int b = 0; b < NBATCH; ++b) acc[b] = fmaf(Qs[b][e], wq, acc[b]);
  }
#pragma unroll
  for (int b = 0; b < NBATCH; ++b) atomicAdd(&q2[b * DDIM + d], acc[b]);
}

// ---------------- K0a-2: u[b,e] = Wk[e,:] . q2[b,:]  (wave per output) -----
__global__ __launch_bounds__(256) void k_qu2(const float* __restrict__ q2,
    const float* __restrict__ Wk, float* __restrict__ u) {
  int wid = threadIdx.x >> 6, lane = threadIdx.x & 63;
  int idx = blockIdx.x * 4 + wid;          // 0..8191
  int b = idx >> 9, e = idx & 511;
  const float* wr = Wk + e * DDIM + lane * 8;
  const float* qr = q2 + b * DDIM + lane * 8;
  float4 w0 = *reinterpret_cast<const float4*>(wr);
  float4 w1 = *reinterpret_cast<const float4*>(wr + 4);
  float4 p0 = *reinterpret_cast<const float4*>(qr);
  float4 p1 = *reinterpret_cast<const float4*>(qr + 4);
  float dot = w0.x * p0.x + w0.y * p0.y + w0.z * p0.z + w0.w * p0.w
            + w1.x * p1.x + w1.y * p1.y + w1.z * p1.z + w1.w * p1.w;
#pragma unroll
  for (int off = 32; off; off >>= 1) dot += __shfl_xor(dot, off);
  if (lane == 0) u[b * DDIM + e] = dot;
}

// ---------------- K0b: W_v -> bf16, MFMA-fragment-swizzled ----------------
// chunk index = kb*32 + ni ; lane l holds B[k=kb*32+(l>>4)*8+j][n=ni*16+(l&15)]
__global__ void k_wswz(const float* __restrict__ Wv, u16* __restrict__ Wf) {
  int blk = blockIdx.x;      // 0..511
  int l = threadIdx.x;       // 0..63
  int kb = blk >> 5, ni = blk & 31;
  int n = ni * 16 + (l & 15);
  int k0 = kb * 32 + (l >> 4) * 8;
  union { short8v v; u16 s[8]; } tmp;
#pragma unroll
  for (int j = 0; j < 8; ++j) tmp.s[j] = f2bf(Wv[(k0 + j) * DDIM + n]);
  *reinterpret_cast<short8v*>(Wf + (blk * 64 + l) * 8) = tmp.v;
}

// ---------------- K1: s[b,k] = K[b,k,:].u[b] / temp  (1 wave/row) ----------
__global__ __launch_bounds__(256) void k_scores(const float* __restrict__ Kin,
    const float* __restrict__ u, float* __restrict__ s) {
  int wid = threadIdx.x >> 6, lane = threadIdx.x & 63;
  int row = blockIdx.x * 4 + wid;        // < 32768
  int b = row >> 11;
  const float* kr = Kin + row * DDIM + lane * 8;
  const float* ur = u + b * DDIM + lane * 8;
  float4 k0 = *reinterpret_cast<const float4*>(kr);
  float4 k1 = *reinterpret_cast<const float4*>(kr + 4);
  float4 u0 = *reinterpret_cast<const float4*>(ur);
  float4 u1 = *reinterpret_cast<const float4*>(ur + 4);
  float dot = k0.x * u0.x + k0.y * u0.y + k0.z * u0.z + k0.w * u0.w
            + k1.x * u1.x + k1.y * u1.y + k1.z * u1.z + k1.w * u1.w;
#pragma unroll
  for (int off = 32; off; off >>= 1) dot += __shfl_xor(dot, off);
  if (lane == 0) s[row] = dot * TEMP_INV;
}

// ---------------- K1b: per-batch max, w = exp(s - M) ----------------
__global__ __launch_bounds__(256) void k_expw(const float* __restrict__ s,
    float* __restrict__ w) {
  int b = blockIdx.x, t = threadIdx.x;
  __shared__ float red[4];
  float v[8];
  float m = -3e38f;
#pragma unroll
  for (int i = 0; i < 8; ++i) { v[i] = s[b * KLEN + t * 8 + i]; m = fmaxf(m, v[i]); }
#pragma unroll
  for (int off = 32; off; off >>= 1) m = fmaxf(m, __shfl_xor(m, off));
  if ((t & 63) == 0) red[t >> 6] = m;
  __syncthreads();
  float M = fmaxf(fmaxf(red[0], red[1]), fmaxf(red[2], red[3]));
#pragma unroll
  for (int i = 0; i < 8; ++i) w[b * KLEN + t * 8 + i] = __expf(v[i] - M);
}

// ---------------- K2: V' = V @ W_v  (bf16 MFMA 16x16x32, 128x128 tile) -----
__global__ __launch_bounds__(256, 2) void k_gemm(const float* __restrict__ V,
    const u16* __restrict__ Wf, u16* __restrict__ Vp) {
  int rt = blockIdx.x;   // 0..255 : 128 rows
  int ct = blockIdx.y;   // 0..3   : 128 cols
  __shared__ __align__(16) u16 Asm[4096];   // [mi(8)][lane(64)][8] bf16
  __shared__ __align__(16) u16 Bsm[4096];   // [ni(8)][lane(64)][8] bf16
  int t = threadIdx.x;
  int wid = t >> 6, lane = t & 63;
  int wm = wid >> 1, wn = wid & 1;

  f32x4 zero4 = {0.f, 0.f, 0.f, 0.f};
  f32x4 acc[4][4];
#pragma unroll
  for (int i = 0; i < 4; ++i)
#pragma unroll
    for (int j = 0; j < 4; ++j) acc[i][j] = zero4;

  int m_ = t >> 2;            // 0..63
  int k0_ = (t & 3) * 8;      // 0,8,16,24
  const float* Abase = V + rt * 128 * DDIM;

  for (int kb = 0; kb < 16; ++kb) {
    __syncthreads();
    // stage A: fp32 load -> bf16 -> fragment-linear LDS
#pragma unroll
    for (int half = 0; half < 2; ++half) {
      int mm = m_ + half * 64;
      const float* src = Abase + mm * DDIM + kb * 32 + k0_;
      float4 f0 = *reinterpret_cast<const float4*>(src);
      float4 f1 = *reinterpret_cast<const float4*>(src + 4);
      union { short8v v; u16 sb[8]; } tmp;
      tmp.sb[0] = f2bf(f0.x); tmp.sb[1] = f2bf(f0.y);
      tmp.sb[2] = f2bf(f0.z); tmp.sb[3] = f2bf(f0.w);
      tmp.sb[4] = f2bf(f1.x); tmp.sb[5] = f2bf(f1.y);
      tmp.sb[6] = f2bf(f1.z); tmp.sb[7] = f2bf(f1.w);
      int idx = (((mm >> 4) << 6) + ((t & 3) << 4) + (mm & 15)) << 3;
      *reinterpret_cast<short8v*>(&Asm[idx]) = tmp.v;
    }
    // stage B: pre-swizzled bf16, 16B per thread, 2 chunks
    {
      int i2 = t;
      *reinterpret_cast<short8v*>(&Bsm[i2 * 8]) =
          *reinterpret_cast<const short8v*>(Wf + ((kb * 32 + ct * 8) * 64 + i2) * 8);
      i2 = t + 256;
      *reinterpret_cast<short8v*>(&Bsm[i2 * 8]) =
          *reinterpret_cast<const short8v*>(Wf + ((kb * 32 + ct * 8) * 64 + i2) * 8);
    }
    __syncthreads();
    short8v af[4], bfr[4];
#pragma unroll
    for (int i = 0; i < 4; ++i)
      af[i] = *reinterpret_cast<const short8v*>(&Asm[((wm * 4 + i) * 64 + lane) * 8]);
#pragma unroll
    for (int j = 0; j < 4; ++j)
      bfr[j] = *reinterpret_cast<const short8v*>(&Bsm[((wn * 4 + j) * 64 + lane) * 8]);
#pragma unroll
    for (int i = 0; i < 4; ++i)
#pragma unroll
      for (int j = 0; j < 4; ++j)
        acc[i][j] = __builtin_amdgcn_mfma_f32_16x16x32_bf16(af[i], bfr[j], acc[i][j], 0, 0, 0);
  }
  // epilogue: D[row=(l>>4)*4+r][col=l&15] per fragment
  int r0 = rt * 128 + wm * 64;
  int c0 = ct * 128 + wn * 64;
#pragma unroll
  for (int i = 0; i < 4; ++i)
#pragma unroll
    for (int j = 0; j < 4; ++j)
#pragma unroll
      for (int r = 0; r < 4; ++r) {
        int row = r0 + i * 16 + (lane >> 4) * 4 + r;
        int col = c0 + j * 16 + (lane & 15);
        Vp[row * DDIM + col] = f2bf(acc[i][j][r]);
      }
}

// ---------------- K3 (pass A): per-tile weighted / unweighted sums ---------
__global__ __launch_bounds__(512) void k_tilesum(const u16* __restrict__ Vp,
    const float* __restrict__ w, float* __restrict__ S, float* __restrict__ U,
    float* __restrict__ z) {
  int bt = blockIdx.x;          // b*NTILE + t ; global row base = bt*TROWS
  int d = threadIdx.x;
  int krow0 = bt * TROWS;
  const float* wrow = w + krow0;
  const u16* vbase = Vp + krow0 * DDIM + d;
  float Sa = 0.f, Ua = 0.f, za = 0.f;
#pragma unroll 4
  for (int r = 0; r < TROWS; ++r) {
    float wk = wrow[r];
    float v = bf2f(vbase[r * DDIM]);
    Sa = fmaf(wk, v, Sa);
    Ua += v;
    za += wk;
  }
  S[bt * DDIM + d] = Sa;
  U[bt * DDIM + d] = Ua;
  if (d == 0) z[bt] = za;
}

// ---------------- K4: exclusive prefix over tiles + column mean ------------
// grid 128 = 16 b x 8 d-chunks; 64 threads, one d per thread.
__global__ __launch_bounds__(64) void k_prefix(const float* __restrict__ S,
    const float* __restrict__ U, const float* __restrict__ z,
    float* __restrict__ base_, float* __restrict__ zbase,
    float* __restrict__ meanVp) {
  int b = blockIdx.x >> 3;
  int dc = blockIdx.x & 7;
  int d = dc * 64 + threadIdx.x;
  float acc = 0.f, tot = 0.f, zacc = 0.f;
  for (int tt = 0; tt < NTILE; ++tt) {
    int bt = b * NTILE + tt;
    base_[bt * DDIM + d] = acc;
    if (dc == 0 && threadIdx.x == 0) zbase[bt] = zacc;
    acc += S[bt * DDIM + d];
    zacc += z[bt];
    tot += U[bt * DDIM + d];
  }
  meanVp[b * DDIM + d] = tot * (1.0f / KLEN);
}

// ---------------- K5 (pass B): in-tile scan + V-add + LayerNorm ------------
__global__ __launch_bounds__(512, 2) void k_scan(const u16* __restrict__ Vp,
    const float* __restrict__ Vin, const float* __restrict__ w,
    const int* __restrict__ mask, const float* __restrict__ base_,
    const float* __restrict__ zbase, const float* __restrict__ meanVp,
    const float* __restrict__ gamma, const float* __restrict__ beta,
    float* __restrict__ out) {
  int bt = blockIdx.x;
  int b = bt >> 6;
  int d = threadIdx.x;
  __shared__ float xs[TROWS][DDIM];   // 64 KiB
  float acc = base_[bt * DDIM + d];
  float zacc = zbase[bt];
  float mv = meanVp[b * DDIM + d];
  int krow0 = bt * TROWS;
  for (int r = 0; r < TROWS; ++r) {
    int k = krow0 + r;
    float wk = w[k];
    zacc += wk;
    float v_ = bf2f(Vp[k * DDIM + d]);
    acc = fmaf(wk, v_, acc);
    float vatt = mask[k] ? mv : acc * __builtin_amdgcn_rcpf(zacc);
    xs[r][d] = Vin[k * DDIM + d] + vatt;
  }
  __syncthreads();
  // LN phase: lane l handles cols [l*4, l*4+3] and [256+l*4, 256+l*4+3]
  // (contiguous 1024B per wave per ds_read_b128 -> no bank conflicts)
  int wid = d >> 6, lane = d & 63;
  float4 g0 = *reinterpret_cast<const float4*>(gamma + lane * 4);
  float4 g1 = *reinterpret_cast<const float4*>(gamma + 256 + lane * 4);
  float4 b0 = *reinterpret_cast<const float4*>(beta + lane * 4);
  float4 b1 = *reinterpret_cast<const float4*>(beta + 256 + lane * 4);
#pragma unroll
  for (int rr = 0; rr < 4; ++rr) {
    int r = wid * 4 + rr;
    float4 x0 = *reinterpret_cast<const float4*>(&xs[r][lane * 4]);
    float4 x1 = *reinterpret_cast<const float4*>(&xs[r][256 + lane * 4]);
    float sum = x0.x + x0.y + x0.z + x0.w + x1.x + x1.y + x1.z + x1.w;
    float sq = x0.x * x0.x + x0.y * x0.y + x0.z * x0.z + x0.w * x0.w
             + x1.x * x1.x + x1.y * x1.y + x1.z * x1.z + x1.w * x1.w;
#pragma unroll
    for (int off = 32; off; off >>= 1) {
      sum += __shfl_xor(sum, off);
      sq += __shfl_xor(sq, off);
    }
    float mu = sum * (1.0f / DDIM);
    float var = sq * (1.0f / DDIM) - mu * mu;
    float rstd = rsqrtf(var + 1e-5f);
    int k = krow0 + r;
    float* orow = out + k * DDIM;
    float4 o0, o1;
    o0.x = (x0.x - mu) * rstd * g0.x + b0.x;
    o0.y = (x0.y - mu) * rstd * g0.y + b0.y;
    o0.z = (x0.z - mu) * rstd * g0.z + b0.z;
    o0.w = (x0.w - mu) * rstd * g0.w + b0.w;
    o1.x = (x1.x - mu) * rstd * g1.x + b1.x;
    o1.y = (x1.y - mu) * rstd * g1.y + b1.y;
    o1.z = (x1.z - mu) * rstd * g1.z + b1.z;
    o1.w = (x1.w - mu) * rstd * g1.w + b1.w;
    *reinterpret_cast<float4*>(orow + lane * 4) = o0;
    *reinterpret_cast<float4*>(orow + 256 + lane * 4) = o1;
  }
}

extern "C" void kernel_launch(void* const* d_in, const int* in_sizes, int n_in,
                              void* d_out, int out_size, void* d_ws, size_t ws_size,
                              hipStream_t stream) {
  const float* Q     = (const float*)d_in[0];
  const float* Kin   = (const float*)d_in[1];
  const float* Vin   = (const float*)d_in[2];
  const int*   mask  = (const int*)d_in[3];
  const float* Wq    = (const float*)d_in[4];
  const float* Wk    = (const float*)d_in[5];
  const float* Wv    = (const float*)d_in[6];
  const float* gamma = (const float*)d_in[7];
  const float* beta  = (const float*)d_in[8];
  float* out = (float*)d_out;

  char* p = (char*)d_ws;
  float* q2     = (float*)p; p += NBATCH * DDIM * 4;
  float* u      = (float*)p; p += NBATCH * DDIM * 4;
  u16*   Wf     = (u16*)p;   p += DDIM * DDIM * 2;
  float* s      = (float*)p; p += NBATCH * KLEN * 4;
  float* w      = (float*)p; p += NBATCH * KLEN * 4;
  float* S      = (float*)p; p += NBATCH * NTILE * DDIM * 4;
  float* U      = (float*)p; p += NBATCH * NTILE * DDIM * 4;
  float* base_  = (float*)p; p += NBATCH * NTILE * DDIM * 4;
  float* z      = (float*)p; p += NBATCH * NTILE * 4;
  float* zbase  = (float*)p; p += NBATCH * NTILE * 4;
  float* meanVp = (float*)p; p += NBATCH * DDIM * 4;
  u16*   Vp     = (u16*)p;   p += (size_t)NBATCH * KLEN * DDIM * 2;

  hipMemsetAsync(q2, 0, NBATCH * DDIM * 4, stream);
  k_qu1<<<64, 64, 0, stream>>>(Q, Wq, q2);
  k_qu2<<<(NBATCH * DDIM) / 4, 256, 0, stream>>>(q2, Wk, u);
  k_wswz<<<512, 64, 0, stream>>>(Wv, Wf);
  k_scores<<<(NBATCH * KLEN) / 4, 256, 0, stream>>>(Kin, u, s);
  k_expw<<<NBATCH, 256, 0, stream>>>(s, w);
  k_gemm<<<dim3(256, 4), 256, 0, stream>>>(Vin, Wf, Vp);
  k_tilesum<<<NBATCH * NTILE, 512, 0, stream>>>(Vp, w, S, U, z);
  k_prefix<<<128, 64, 0, stream>>>(S, U, z, base_, zbase, meanVp);
  k_scan<<<NBATCH * NTILE, 512, 0, stream>>>(Vp, Vin, w, mask, base_, zbase,
                                             meanVp, gamma, beta, out);
}